// Round 1
// baseline (205.612 us; speedup 1.0000x reference)
//
#include <hip/hip_runtime.h>
#include <hip/hip_bf16.h>

// Causal scaled-dot-product attention, B=2 H=16 S=2048 D=64, fp32 in/out.
// Flash-attention: WG = 4 waves = 64 Q rows of one (b,h); KV tiles of 64
// staged in LDS as bf16; mfma_f32_16x16x32_bf16 for QK^T and PV.

#define S_ 2048
#define D_ 64

typedef __bf16 bf16x8 __attribute__((ext_vector_type(8)));
typedef float f32x4 __attribute__((ext_vector_type(4)));
typedef unsigned short u16x4 __attribute__((ext_vector_type(4)));

static __device__ __forceinline__ unsigned short f2bf(float f) {
    union { float f; unsigned u; } v; v.f = f;
    unsigned r = v.u + 0x7FFFu + ((v.u >> 16) & 1u);   // round-to-nearest-even
    return (unsigned short)(r >> 16);
}

__global__ __launch_bounds__(256)
void attn_fwd(const float* __restrict__ Q, const float* __restrict__ K,
              const float* __restrict__ V, float* __restrict__ O) {
    const int tid  = threadIdx.x;
    const int wave = tid >> 6;
    const int lane = tid & 63;
    const int lg   = lane >> 4;   // 16-lane group 0..3
    const int lr   = lane & 15;

    const int wg   = blockIdx.x;
    const int bh   = wg & 31;           // 32 (b,h) pairs
    const int qblk = 31 - (wg >> 5);    // heavy (late) q-blocks dispatch first
    const int q0   = qblk << 6;

    const float* Qb = Q + (size_t)bh * S_ * D_;
    const float* Kb = K + (size_t)bh * S_ * D_;
    const float* Vb = V + (size_t)bh * S_ * D_;
    float*       Ob = O + (size_t)bh * S_ * D_;

    __shared__ unsigned short Kl[64][72];      // [kv][d]   bf16, +8 pad (16B-aligned rows)
    __shared__ unsigned short Vt[64][72];      // [d][kv]   bf16 (transposed)
    __shared__ unsigned short Pl[4][16][72];   // per-wave P roundtrip [q][kv]

    // ---- Q fragments (A-layout: row = lane&15, k = 8*(lane>>4)+i per 32-k tile)
    const float qscale = 0.18033688011112042f;   // log2(e) / 8
    bf16x8 qa[2];
    {
        const int qrow = q0 + wave * 16 + lr;
        #pragma unroll
        for (int kt = 0; kt < 2; ++kt) {
            const float* src = Qb + qrow * D_ + kt * 32 + lg * 8;
            float4 x = *reinterpret_cast<const float4*>(src);
            float4 y = *reinterpret_cast<const float4*>(src + 4);
            union { unsigned short u[8]; bf16x8 v; } pk;
            pk.u[0] = f2bf(x.x * qscale); pk.u[1] = f2bf(x.y * qscale);
            pk.u[2] = f2bf(x.z * qscale); pk.u[3] = f2bf(x.w * qscale);
            pk.u[4] = f2bf(y.x * qscale); pk.u[5] = f2bf(y.y * qscale);
            pk.u[6] = f2bf(y.z * qscale); pk.u[7] = f2bf(y.w * qscale);
            qa[kt] = pk.v;
        }
    }

    f32x4 oacc[4];
    #pragma unroll
    for (int i = 0; i < 4; ++i) oacc[i] = {0.f, 0.f, 0.f, 0.f};
    float m_[4], l_[4];
    #pragma unroll
    for (int r = 0; r < 4; ++r) { m_[r] = -__builtin_inff(); l_[r] = 0.f; }

    const int nkv = (q0 >> 6) + 1;
    for (int t = 0; t < nkv; ++t) {
        const int kvbase = t << 6;
        __syncthreads();   // protect previous tile's LDS reads

        // ---- stage K (row-major) and V (transposed) as bf16; coalesced f32 reads
        #pragma unroll
        for (int k = 0; k < 4; ++k) {
            const int flat = (k << 10) + (tid << 2);     // f32 index within 64x64 tile
            const int kv = flat >> 6;
            const int d  = flat & 63;
            float4 kx = *reinterpret_cast<const float4*>(Kb + (size_t)(kvbase + kv) * D_ + d);
            u16x4 kp = { f2bf(kx.x), f2bf(kx.y), f2bf(kx.z), f2bf(kx.w) };
            *reinterpret_cast<u16x4*>(&Kl[kv][d]) = kp;
            float4 vx = *reinterpret_cast<const float4*>(Vb + (size_t)(kvbase + kv) * D_ + d);
            Vt[d + 0][kv] = f2bf(vx.x);
            Vt[d + 1][kv] = f2bf(vx.y);
            Vt[d + 2][kv] = f2bf(vx.z);
            Vt[d + 3][kv] = f2bf(vx.w);
        }
        __syncthreads();

        // ---- S = Q K^T  (16 q-rows x 64 kv), fp32 acc
        f32x4 sacc[4];
        #pragma unroll
        for (int kvt = 0; kvt < 4; ++kvt) {
            sacc[kvt] = {0.f, 0.f, 0.f, 0.f};
            #pragma unroll
            for (int kt = 0; kt < 2; ++kt) {
                bf16x8 kb = *reinterpret_cast<const bf16x8*>(&Kl[kvt * 16 + lr][kt * 32 + lg * 8]);
                sacc[kvt] = __builtin_amdgcn_mfma_f32_16x16x32_bf16(qa[kt], kb, sacc[kvt], 0, 0, 0);
            }
        }

        // ---- causal mask (only the diagonal tile)
        if (t == nkv - 1) {
            #pragma unroll
            for (int kvt = 0; kvt < 4; ++kvt) {
                const int kvg = kvbase + kvt * 16 + lr;      // C/D col = lane&15
                #pragma unroll
                for (int r = 0; r < 4; ++r) {
                    const int qg = q0 + wave * 16 + lg * 4 + r;  // C/D row
                    if (kvg > qg) sacc[kvt][r] = -__builtin_inff();
                }
            }
        }

        // ---- online softmax (base-2 domain; Q was pre-scaled by log2e/8)
        float al[4];
        #pragma unroll
        for (int r = 0; r < 4; ++r) {
            float v = fmaxf(fmaxf(sacc[0][r], sacc[1][r]), fmaxf(sacc[2][r], sacc[3][r]));
            #pragma unroll
            for (int off = 1; off < 16; off <<= 1)
                v = fmaxf(v, __shfl_xor(v, off, 16));
            const float mn = fmaxf(m_[r], v);
            al[r] = __builtin_amdgcn_exp2f(m_[r] - mn);   // first tile: exp2(-inf)=0
            m_[r] = mn;
        }
        #pragma unroll
        for (int kvt = 0; kvt < 4; ++kvt)
            #pragma unroll
            for (int r = 0; r < 4; ++r)
                sacc[kvt][r] = __builtin_amdgcn_exp2f(sacc[kvt][r] - m_[r]);
        #pragma unroll
        for (int r = 0; r < 4; ++r) {
            float s = (sacc[0][r] + sacc[1][r]) + (sacc[2][r] + sacc[3][r]);
            #pragma unroll
            for (int off = 1; off < 16; off <<= 1)
                s += __shfl_xor(s, off, 16);
            l_[r] = l_[r] * al[r] + s;
            #pragma unroll
            for (int dt = 0; dt < 4; ++dt) oacc[dt][r] *= al[r];
        }

        // ---- P: D-layout regs -> LDS -> A-layout frags (per-wave buffer, no barrier)
        #pragma unroll
        for (int kvt = 0; kvt < 4; ++kvt)
            #pragma unroll
            for (int r = 0; r < 4; ++r)
                Pl[wave][lg * 4 + r][kvt * 16 + lr] = f2bf(sacc[kvt][r]);

        bf16x8 pa0 = *reinterpret_cast<const bf16x8*>(&Pl[wave][lr][lg * 8]);
        bf16x8 pa1 = *reinterpret_cast<const bf16x8*>(&Pl[wave][lr][32 + lg * 8]);

        // ---- O += P V   (B-frag from transposed V: contiguous ds_read_b128)
        #pragma unroll
        for (int dt = 0; dt < 4; ++dt) {
            bf16x8 vb0 = *reinterpret_cast<const bf16x8*>(&Vt[dt * 16 + lr][lg * 8]);
            oacc[dt] = __builtin_amdgcn_mfma_f32_16x16x32_bf16(pa0, vb0, oacc[dt], 0, 0, 0);
            bf16x8 vb1 = *reinterpret_cast<const bf16x8*>(&Vt[dt * 16 + lr][32 + lg * 8]);
            oacc[dt] = __builtin_amdgcn_mfma_f32_16x16x32_bf16(pa1, vb1, oacc[dt], 0, 0, 0);
        }
    }

    // ---- epilogue: O / l
    #pragma unroll
    for (int r = 0; r < 4; ++r) {
        const int qrow = q0 + wave * 16 + lg * 4 + r;
        const float inv = 1.0f / l_[r];
        #pragma unroll
        for (int dt = 0; dt < 4; ++dt)
            Ob[(size_t)qrow * D_ + dt * 16 + lr] = oacc[dt][r] * inv;
    }
}

extern "C" void kernel_launch(void* const* d_in, const int* in_sizes, int n_in,
                              void* d_out, int out_size, void* d_ws, size_t ws_size,
                              hipStream_t stream) {
    const float* Q = (const float*)d_in[0];
    const float* K = (const float*)d_in[1];
    const float* V = (const float*)d_in[2];
    // d_in[3] = mask: exact causal tril by construction -> applied analytically.
    float* O = (float*)d_out;
    dim3 grid(1024), block(256);
    hipLaunchKernelGGL(attn_fwd, grid, block, 0, stream, Q, K, V, O);
}

// Round 2
// 164.947 us; speedup vs baseline: 1.2465x; 1.2465x over previous
//
#include <hip/hip_runtime.h>
#include <hip/hip_bf16.h>

// Causal SDPA, B=2 H=16 S=2048 D=64, fp32 in/out.
// R2: prep kernels convert K->bf16 and V->bf16-transposed into d_ws; the
// attention kernel stages tiles with global_load_lds (16B) into linear LDS
// using XOR-swizzled global source chunks, double-buffered.

#define S_ 2048
#define D_ 64
#define NBH 32

typedef __bf16 bf16x8 __attribute__((ext_vector_type(8)));
typedef float f32x4 __attribute__((ext_vector_type(4)));
typedef unsigned short u16x4 __attribute__((ext_vector_type(4)));
typedef unsigned short u16x8 __attribute__((ext_vector_type(8)));

static __device__ __forceinline__ unsigned short f2bf(float f) {
    union { float f; unsigned u; } v; v.f = f;
    unsigned r = v.u + 0x7FFFu + ((v.u >> 16) & 1u);   // RNE
    return (unsigned short)(r >> 16);
}

// ---- prep: K f32 -> bf16, flat copy (coalesced float4 -> u16x4)
__global__ __launch_bounds__(256)
void prep_k(const float* __restrict__ K, unsigned short* __restrict__ Kbf) {
    #pragma unroll
    for (int i = 0; i < 2; ++i) {
        const int p = blockIdx.x * 512 + i * 256 + threadIdx.x;   // float4 idx
        float4 x = reinterpret_cast<const float4*>(K)[p];
        u16x4 o = { f2bf(x.x), f2bf(x.y), f2bf(x.z), f2bf(x.w) };
        reinterpret_cast<u16x4*>(Kbf)[p] = o;
    }
}

// ---- prep: V f32 [bh][s][d] -> bf16 transposed Vt [bh][d][s], LDS tile transpose
__global__ __launch_bounds__(256)
void prep_v(const float* __restrict__ V, unsigned short* __restrict__ Vt) {
    __shared__ float Vl[64][65];
    const int bh = blockIdx.x >> 5;
    const int kvbase = (blockIdx.x & 31) << 6;
    const float* Vb = V + (size_t)bh * S_ * D_ + (size_t)kvbase * D_;
    #pragma unroll
    for (int i = 0; i < 4; ++i) {
        const int flat = i * 1024 + threadIdx.x * 4;
        const int kv = flat >> 6, d = flat & 63;
        float4 x = *reinterpret_cast<const float4*>(Vb + kv * D_ + d);
        Vl[kv][d] = x.x; Vl[kv][d + 1] = x.y; Vl[kv][d + 2] = x.z; Vl[kv][d + 3] = x.w;
    }
    __syncthreads();
    unsigned short* Vo = Vt + (size_t)bh * D_ * S_;
    #pragma unroll
    for (int i = 0; i < 2; ++i) {
        const int p = i * 256 + threadIdx.x;   // 16B chunk within [64][128B] tile
        const int d = p >> 3, c = p & 7;
        u16x8 o;
        #pragma unroll
        for (int j = 0; j < 8; ++j) o[j] = f2bf(Vl[c * 8 + j][d]);
        *reinterpret_cast<u16x8*>(Vo + d * S_ + kvbase + c * 8) = o;
    }
}

// ---- attention
__global__ __launch_bounds__(256)
void attn_fwd2(const float* __restrict__ Q, const unsigned short* __restrict__ Kbf,
               const unsigned short* __restrict__ Vtbf, float* __restrict__ O) {
    const int tid  = threadIdx.x;
    const int wave = tid >> 6;
    const int lane = tid & 63;
    const int lg   = lane >> 4;
    const int lr   = lane & 15;

    const int wg   = blockIdx.x;
    const int bh   = wg & 31;
    const int qblk = 31 - (wg >> 5);    // heavy q-blocks dispatch first
    const int q0   = qblk << 6;

    const float*          Qb = Q    + (size_t)bh * S_ * D_;
    const unsigned short* Kg = Kbf  + (size_t)bh * S_ * D_;
    const unsigned short* Vg = Vtbf + (size_t)bh * D_ * S_;
    float*                Ob = O    + (size_t)bh * S_ * D_;

    // Linear LDS (global_load_lds needs contiguous dest); swizzle lives in the
    // global source chunk index and in the ds_read address (chunk ^= row&7).
    __shared__ __align__(16) unsigned short Kl[2][4096];   // [64][64] bf16 per buf
    __shared__ __align__(16) unsigned short Vl[2][4096];   // [64 d][64 kv] per buf
    __shared__ unsigned short Pl[4][16][72];               // per-wave P roundtrip

    // ---- Q fragments (A-layout), scaled by log2(e)/8 for base-2 softmax
    const float qscale = 0.18033688011112042f;
    bf16x8 qa[2];
    {
        const int qrow = q0 + wave * 16 + lr;
        #pragma unroll
        for (int kt = 0; kt < 2; ++kt) {
            const float* src = Qb + qrow * D_ + kt * 32 + lg * 8;
            float4 x = *reinterpret_cast<const float4*>(src);
            float4 y = *reinterpret_cast<const float4*>(src + 4);
            union { unsigned short u[8]; bf16x8 v; } pk;
            pk.u[0] = f2bf(x.x * qscale); pk.u[1] = f2bf(x.y * qscale);
            pk.u[2] = f2bf(x.z * qscale); pk.u[3] = f2bf(x.w * qscale);
            pk.u[4] = f2bf(y.x * qscale); pk.u[5] = f2bf(y.y * qscale);
            pk.u[6] = f2bf(y.z * qscale); pk.u[7] = f2bf(y.w * qscale);
            qa[kt] = pk.v;
        }
    }

    f32x4 oacc[4];
    #pragma unroll
    for (int i = 0; i < 4; ++i) oacc[i] = {0.f, 0.f, 0.f, 0.f};
    float m_[4], l_[4];
    #pragma unroll
    for (int r = 0; r < 4; ++r) { m_[r] = -__builtin_inff(); l_[r] = 0.f; }

    const int nkv = (q0 >> 6) + 1;

    // stage tile t of K and Vt into buffer buf; 2 chunks/lane each
    auto stage = [&](int buf, int t) {
        #pragma unroll
        for (int i = 0; i < 2; ++i) {
            const int p   = wave * 128 + i * 64 + lane;    // 16B chunk index 0..511
            const int row = p >> 3, c = p & 7;
            const int sc  = c ^ (row & 7);                 // pre-swizzled source
            const unsigned short* gk = Kg + (size_t)(t * 64 + row) * 64 + sc * 8;
            __builtin_amdgcn_global_load_lds(
                (const __attribute__((address_space(1))) void*)gk,
                (__attribute__((address_space(3))) void*)&Kl[buf][(wave * 128 + i * 64) * 8],
                16, 0, 0);
            const unsigned short* gv = Vg + (size_t)row * S_ + t * 64 + sc * 8;
            __builtin_amdgcn_global_load_lds(
                (const __attribute__((address_space(1))) void*)gv,
                (__attribute__((address_space(3))) void*)&Vl[buf][(wave * 128 + i * 64) * 8],
                16, 0, 0);
        }
    };

    stage(0, 0);
    __syncthreads();

    for (int t = 0; t < nkv; ++t) {
        if (t + 1 < nkv) stage((t + 1) & 1, t + 1);        // prefetch next tile
        const unsigned short* Kb_ = Kl[t & 1];
        const unsigned short* Vb_ = Vl[t & 1];
        const int kvbase = t << 6;

        // ---- S = Q K^T (swizzled ds_read_b128: conflict-free)
        f32x4 sacc[4];
        #pragma unroll
        for (int kvt = 0; kvt < 4; ++kvt) {
            sacc[kvt] = {0.f, 0.f, 0.f, 0.f};
            #pragma unroll
            for (int kt = 0; kt < 2; ++kt) {
                bf16x8 kb = *reinterpret_cast<const bf16x8*>(
                    &Kb_[((kvt * 16 + lr) * 8 + ((kt * 4 + lg) ^ (lr & 7))) * 8]);
                sacc[kvt] = __builtin_amdgcn_mfma_f32_16x16x32_bf16(qa[kt], kb, sacc[kvt], 0, 0, 0);
            }
        }

        // ---- causal mask (diagonal tile only)
        if (t == nkv - 1) {
            #pragma unroll
            for (int kvt = 0; kvt < 4; ++kvt) {
                const int kvg = kvbase + kvt * 16 + lr;
                #pragma unroll
                for (int r = 0; r < 4; ++r) {
                    const int qg = q0 + wave * 16 + lg * 4 + r;
                    if (kvg > qg) sacc[kvt][r] = -__builtin_inff();
                }
            }
        }

        // ---- online softmax (base-2)
        float al[4];
        #pragma unroll
        for (int r = 0; r < 4; ++r) {
            float v = fmaxf(fmaxf(sacc[0][r], sacc[1][r]), fmaxf(sacc[2][r], sacc[3][r]));
            #pragma unroll
            for (int off = 1; off < 16; off <<= 1)
                v = fmaxf(v, __shfl_xor(v, off, 16));
            const float mn = fmaxf(m_[r], v);
            al[r] = __builtin_amdgcn_exp2f(m_[r] - mn);
            m_[r] = mn;
        }
        #pragma unroll
        for (int kvt = 0; kvt < 4; ++kvt)
            #pragma unroll
            for (int r = 0; r < 4; ++r)
                sacc[kvt][r] = __builtin_amdgcn_exp2f(sacc[kvt][r] - m_[r]);
        #pragma unroll
        for (int r = 0; r < 4; ++r) {
            float s = (sacc[0][r] + sacc[1][r]) + (sacc[2][r] + sacc[3][r]);
            #pragma unroll
            for (int off = 1; off < 16; off <<= 1)
                s += __shfl_xor(s, off, 16);
            l_[r] = l_[r] * al[r] + s;
            #pragma unroll
            for (int dt = 0; dt < 4; ++dt) oacc[dt][r] *= al[r];
        }

        // ---- P: D-layout regs -> per-wave LDS -> A-layout frags
        #pragma unroll
        for (int kvt = 0; kvt < 4; ++kvt)
            #pragma unroll
            for (int r = 0; r < 4; ++r)
                Pl[wave][lg * 4 + r][kvt * 16 + lr] = f2bf(sacc[kvt][r]);

        bf16x8 pa0 = *reinterpret_cast<const bf16x8*>(&Pl[wave][lr][lg * 8]);
        bf16x8 pa1 = *reinterpret_cast<const bf16x8*>(&Pl[wave][lr][32 + lg * 8]);

        // ---- O += P V (B-frag from transposed V, swizzled)
        #pragma unroll
        for (int dt = 0; dt < 4; ++dt) {
            bf16x8 vb0 = *reinterpret_cast<const bf16x8*>(
                &Vb_[((dt * 16 + lr) * 8 + ((0 * 4 + lg) ^ (lr & 7))) * 8]);
            oacc[dt] = __builtin_amdgcn_mfma_f32_16x16x32_bf16(pa0, vb0, oacc[dt], 0, 0, 0);
            bf16x8 vb1 = *reinterpret_cast<const bf16x8*>(
                &Vb_[((dt * 16 + lr) * 8 + ((1 * 4 + lg) ^ (lr & 7))) * 8]);
            oacc[dt] = __builtin_amdgcn_mfma_f32_16x16x32_bf16(pa1, vb1, oacc[dt], 0, 0, 0);
        }

        __syncthreads();   // staged t+1 landed; all reads of buf t done
    }

    // ---- epilogue
    #pragma unroll
    for (int r = 0; r < 4; ++r) {
        const int qrow = q0 + wave * 16 + lg * 4 + r;
        const float inv = 1.0f / l_[r];
        #pragma unroll
        for (int dt = 0; dt < 4; ++dt)
            Ob[(size_t)qrow * D_ + dt * 16 + lr] = oacc[dt][r] * inv;
    }
}

extern "C" void kernel_launch(void* const* d_in, const int* in_sizes, int n_in,
                              void* d_out, int out_size, void* d_ws, size_t ws_size,
                              hipStream_t stream) {
    const float* Q = (const float*)d_in[0];
    const float* K = (const float*)d_in[1];
    const float* V = (const float*)d_in[2];
    // d_in[3] = mask: exact causal tril -> applied analytically.
    float* O = (float*)d_out;

    unsigned short* Kbf = (unsigned short*)d_ws;                       // 8 MB
    unsigned short* Vt  = Kbf + (size_t)NBH * S_ * D_;                 // 8 MB

    hipLaunchKernelGGL(prep_k,    dim3(2048), dim3(256), 0, stream, K, Kbf);
    hipLaunchKernelGGL(prep_v,    dim3(1024), dim3(256), 0, stream, V, Vt);
    hipLaunchKernelGGL(attn_fwd2, dim3(1024), dim3(256), 0, stream, Q, Kbf, Vt, O);
}

// Round 3
// 159.212 us; speedup vs baseline: 1.2914x; 1.0360x over previous
//
#include <hip/hip_runtime.h>
#include <hip/hip_bf16.h>

// Causal SDPA, B=2 H=16 S=2048 D=64, fp32 in/out.
// R3: paired q-blocks (i, 31-i) per block -> constant 33 tiles/block, grid 512
// fully co-resident; row-sum via ones-MFMA; compiler bf16 casts; defer-max;
// setprio around MFMA clusters; fused prep kernel.

#define S_ 2048
#define D_ 64
#define NBH 32

typedef __bf16 bf16x8 __attribute__((ext_vector_type(8)));
typedef float f32x4 __attribute__((ext_vector_type(4)));
typedef unsigned short u16x4 __attribute__((ext_vector_type(4)));
typedef unsigned short u16x8 __attribute__((ext_vector_type(8)));

static __device__ __forceinline__ unsigned short bfb(float f) {
    return __builtin_bit_cast(unsigned short, (__bf16)f);   // HW RNE cvt
}

// ---- prep: K f32->bf16 flat; V f32 [s][d] -> bf16 transposed [d][s]
__global__ __launch_bounds__(256)
void prep_kv(const float* __restrict__ K, const float* __restrict__ V,
             unsigned short* __restrict__ Kbf, unsigned short* __restrict__ Vt) {
    const int bh = blockIdx.x >> 5;
    const int kvbase = (blockIdx.x & 31) << 6;

    const float* Ks = K + (size_t)bh * S_ * D_ + (size_t)kvbase * D_;
    unsigned short* Kd = Kbf + (size_t)bh * S_ * D_ + (size_t)kvbase * D_;
    #pragma unroll
    for (int i = 0; i < 4; ++i) {
        const int p = i * 256 + threadIdx.x;            // float4 idx, 1024 total
        float4 x = reinterpret_cast<const float4*>(Ks)[p];
        u16x4 o = { bfb(x.x), bfb(x.y), bfb(x.z), bfb(x.w) };
        reinterpret_cast<u16x4*>(Kd)[p] = o;
    }

    __shared__ float Vl[64][65];
    const float* Vb = V + (size_t)bh * S_ * D_ + (size_t)kvbase * D_;
    #pragma unroll
    for (int i = 0; i < 4; ++i) {
        const int flat = i * 1024 + threadIdx.x * 4;
        const int kv = flat >> 6, d = flat & 63;
        float4 x = *reinterpret_cast<const float4*>(Vb + kv * D_ + d);
        Vl[kv][d] = x.x; Vl[kv][d + 1] = x.y; Vl[kv][d + 2] = x.z; Vl[kv][d + 3] = x.w;
    }
    __syncthreads();
    unsigned short* Vo = Vt + (size_t)bh * D_ * S_;
    #pragma unroll
    for (int i = 0; i < 2; ++i) {
        const int p = i * 256 + threadIdx.x;            // 16B chunk in [64][128B]
        const int d = p >> 3, c = p & 7;
        u16x8 o;
        #pragma unroll
        for (int j = 0; j < 8; ++j) o[j] = bfb(Vl[c * 8 + j][d]);
        *reinterpret_cast<u16x8*>(Vo + d * S_ + kvbase + c * 8) = o;
    }
}

// ---- attention
__global__ __launch_bounds__(256)
void attn_fwd3(const float* __restrict__ Q, const unsigned short* __restrict__ Kbf,
               const unsigned short* __restrict__ Vtbf, float* __restrict__ O) {
    const int tid  = threadIdx.x;
    const int wave = tid >> 6;
    const int lane = tid & 63;
    const int lg   = lane >> 4;
    const int lr   = lane & 15;

    const int wg = blockIdx.x;
    const int bh = wg & 31;            // same-bh blocks land on one XCD (stride 32)
    const int pr = wg >> 5;            // 0..15: q-block pair (31-pr, pr) = 33 tiles

    const float*          Qb = Q    + (size_t)bh * S_ * D_;
    const unsigned short* Kg = Kbf  + (size_t)bh * S_ * D_;
    const unsigned short* Vg = Vtbf + (size_t)bh * D_ * S_;
    float*                Ob = O    + (size_t)bh * S_ * D_;

    __shared__ __align__(16) unsigned short Kl[2][4096];   // [64][64] bf16
    __shared__ __align__(16) unsigned short Vl[2][4096];   // [64 d][64 kv] bf16
    __shared__ unsigned short Pl[4][16][72];               // per-wave P roundtrip

    bf16x8 ones;
    #pragma unroll
    for (int i = 0; i < 8; ++i) ones[i] = (__bf16)1.0f;

    auto stage = [&](int buf, int t) {
        #pragma unroll
        for (int i = 0; i < 2; ++i) {
            const int p   = wave * 128 + i * 64 + lane;    // 16B chunk 0..511
            const int row = p >> 3, c = p & 7;
            const int sc  = c ^ (row & 7);                 // pre-swizzled source
            const unsigned short* gk = Kg + (size_t)(t * 64 + row) * 64 + sc * 8;
            __builtin_amdgcn_global_load_lds(
                (const __attribute__((address_space(1))) void*)gk,
                (__attribute__((address_space(3))) void*)&Kl[buf][p * 8], 16, 0, 0);
            const unsigned short* gv = Vg + (size_t)row * S_ + t * 64 + sc * 8;
            __builtin_amdgcn_global_load_lds(
                (const __attribute__((address_space(1))) void*)gv,
                (__attribute__((address_space(3))) void*)&Vl[buf][p * 8], 16, 0, 0);
        }
    };

    const float qscale = 0.18033688011112042f;   // log2(e)/8

    auto run_pass = [&](int q0) {
        bf16x8 qa[2];
        {
            const int qrow = q0 + wave * 16 + lr;
            #pragma unroll
            for (int kt = 0; kt < 2; ++kt) {
                const float* src = Qb + qrow * D_ + kt * 32 + lg * 8;
                float4 x = *reinterpret_cast<const float4*>(src);
                float4 y = *reinterpret_cast<const float4*>(src + 4);
                union { unsigned short u[8]; bf16x8 v; } pk;
                pk.u[0] = bfb(x.x * qscale); pk.u[1] = bfb(x.y * qscale);
                pk.u[2] = bfb(x.z * qscale); pk.u[3] = bfb(x.w * qscale);
                pk.u[4] = bfb(y.x * qscale); pk.u[5] = bfb(y.y * qscale);
                pk.u[6] = bfb(y.z * qscale); pk.u[7] = bfb(y.w * qscale);
                qa[kt] = pk.v;
            }
        }

        f32x4 oacc[4];
        #pragma unroll
        for (int i = 0; i < 4; ++i) oacc[i] = {0.f, 0.f, 0.f, 0.f};
        float m_[4], l_[4];
        #pragma unroll
        for (int r = 0; r < 4; ++r) { m_[r] = -__builtin_inff(); l_[r] = 0.f; }

        const int nkv = (q0 >> 6) + 1;
        stage(0, 0);
        __syncthreads();

        for (int t = 0; t < nkv; ++t) {
            if (t + 1 < nkv) stage((t + 1) & 1, t + 1);
            const unsigned short* Kb_ = Kl[t & 1];
            const unsigned short* Vb_ = Vl[t & 1];
            const int kvbase = t << 6;

            // ---- S = Q K^T
            f32x4 sacc[4];
            __builtin_amdgcn_s_setprio(1);
            #pragma unroll
            for (int kvt = 0; kvt < 4; ++kvt) {
                sacc[kvt] = {0.f, 0.f, 0.f, 0.f};
                #pragma unroll
                for (int kt = 0; kt < 2; ++kt) {
                    bf16x8 kb = *reinterpret_cast<const bf16x8*>(
                        &Kb_[((kvt * 16 + lr) * 8 + ((kt * 4 + lg) ^ (lr & 7))) * 8]);
                    sacc[kvt] = __builtin_amdgcn_mfma_f32_16x16x32_bf16(qa[kt], kb, sacc[kvt], 0, 0, 0);
                }
            }
            __builtin_amdgcn_s_setprio(0);

            // ---- causal mask (diagonal tile only)
            if (t == nkv - 1) {
                #pragma unroll
                for (int kvt = 0; kvt < 4; ++kvt) {
                    const int kvg = kvbase + kvt * 16 + lr;
                    #pragma unroll
                    for (int r = 0; r < 4; ++r) {
                        const int qg = q0 + wave * 16 + lg * 4 + r;
                        if (kvg > qg) sacc[kvt][r] = -__builtin_inff();
                    }
                }
            }

            // ---- online softmax (base-2), defer-max (THR=8 -> P <= 256)
            float pm[4];
            bool resc = false;
            #pragma unroll
            for (int r = 0; r < 4; ++r) {
                float v = fmaxf(fmaxf(sacc[0][r], sacc[1][r]), fmaxf(sacc[2][r], sacc[3][r]));
                #pragma unroll
                for (int off = 1; off < 16; off <<= 1)
                    v = fmaxf(v, __shfl_xor(v, off, 16));
                pm[r] = v;
                resc = resc || (v > m_[r] + 8.0f);
            }
            if (__any((int)resc)) {
                #pragma unroll
                for (int r = 0; r < 4; ++r) {
                    const float mn = fmaxf(m_[r], pm[r]);
                    const float al = __builtin_amdgcn_exp2f(m_[r] - mn);
                    m_[r] = mn;
                    l_[r] *= al;
                    #pragma unroll
                    for (int dt = 0; dt < 4; ++dt) oacc[dt][r] *= al;
                }
            }
            #pragma unroll
            for (int kvt = 0; kvt < 4; ++kvt)
                #pragma unroll
                for (int r = 0; r < 4; ++r)
                    sacc[kvt][r] = __builtin_amdgcn_exp2f(sacc[kvt][r] - m_[r]);

            // ---- P: D-layout regs -> per-wave LDS -> A-layout frags
            #pragma unroll
            for (int kvt = 0; kvt < 4; ++kvt)
                #pragma unroll
                for (int r = 0; r < 4; ++r)
                    Pl[wave][lg * 4 + r][kvt * 16 + lr] = bfb(sacc[kvt][r]);

            bf16x8 pa0 = *reinterpret_cast<const bf16x8*>(&Pl[wave][lr][lg * 8]);
            bf16x8 pa1 = *reinterpret_cast<const bf16x8*>(&Pl[wave][lr][32 + lg * 8]);

            // ---- O += P V ; row-sum via ones-MFMA
            f32x4 ssum = {0.f, 0.f, 0.f, 0.f};
            __builtin_amdgcn_s_setprio(1);
            #pragma unroll
            for (int dt = 0; dt < 4; ++dt) {
                bf16x8 vb0 = *reinterpret_cast<const bf16x8*>(
                    &Vb_[((dt * 16 + lr) * 8 + ((0 * 4 + lg) ^ (lr & 7))) * 8]);
                oacc[dt] = __builtin_amdgcn_mfma_f32_16x16x32_bf16(pa0, vb0, oacc[dt], 0, 0, 0);
                bf16x8 vb1 = *reinterpret_cast<const bf16x8*>(
                    &Vb_[((dt * 16 + lr) * 8 + ((1 * 4 + lg) ^ (lr & 7))) * 8]);
                oacc[dt] = __builtin_amdgcn_mfma_f32_16x16x32_bf16(pa1, vb1, oacc[dt], 0, 0, 0);
            }
            ssum = __builtin_amdgcn_mfma_f32_16x16x32_bf16(pa0, ones, ssum, 0, 0, 0);
            ssum = __builtin_amdgcn_mfma_f32_16x16x32_bf16(pa1, ones, ssum, 0, 0, 0);
            __builtin_amdgcn_s_setprio(0);

            #pragma unroll
            for (int r = 0; r < 4; ++r) l_[r] += ssum[r];

            __syncthreads();   // staged t+1 landed; reads of buf t done
        }

        #pragma unroll
        for (int r = 0; r < 4; ++r) {
            const int qrow = q0 + wave * 16 + lg * 4 + r;
            const float inv = 1.0f / l_[r];
            #pragma unroll
            for (int dt = 0; dt < 4; ++dt)
                Ob[(size_t)qrow * D_ + dt * 16 + lr] = oacc[dt][r] * inv;
        }
    };

    run_pass((31 - pr) << 6);   // heavy member of the pair
    __syncthreads();
    run_pass(pr << 6);          // light member -> total 33 tiles for every block
}

extern "C" void kernel_launch(void* const* d_in, const int* in_sizes, int n_in,
                              void* d_out, int out_size, void* d_ws, size_t ws_size,
                              hipStream_t stream) {
    const float* Q = (const float*)d_in[0];
    const float* K = (const float*)d_in[1];
    const float* V = (const float*)d_in[2];
    // d_in[3] = mask: exact causal tril -> applied analytically.
    float* O = (float*)d_out;

    unsigned short* Kbf = (unsigned short*)d_ws;               // 8 MB
    unsigned short* Vt  = Kbf + (size_t)NBH * S_ * D_;         // 8 MB

    hipLaunchKernelGGL(prep_kv,   dim3(1024), dim3(256), 0, stream, K, V, Kbf, Vt);
    hipLaunchKernelGGL(attn_fwd3, dim3(512),  dim3(256), 0, stream, Q, Kbf, Vt, O);
}

// Round 5
// 153.946 us; speedup vs baseline: 1.3356x; 1.0342x over previous
//
#include <hip/hip_runtime.h>
#include <hip/hip_bf16.h>

// Causal SDPA, B=2 H=16 S=2048 D=64, fp32 in/out.
// R5 = R4 resubmit (container-level infra failure, no kernel evidence):
// swapped QK^T (S^T = K·Q^T) with 32x32x16 MFMA -> lane owns one q-column,
// softmax in-register (31 in-lane ops + 1 shfl_xor(32)); P^T rebuilt in-register
// via half-exchange (no P LDS roundtrip); PV as O^T = V^T·P^T; 2-wave blocks,
// 1024 heavy-first blocks -> 4 independent barrier domains/CU.

#define S_ 2048
#define D_ 64
#define NBH 32

typedef __bf16 bf16x8 __attribute__((ext_vector_type(8)));
typedef float f32x16 __attribute__((ext_vector_type(16)));
typedef unsigned short u16x4 __attribute__((ext_vector_type(4)));
typedef unsigned short u16x8 __attribute__((ext_vector_type(8)));
typedef unsigned int u32;
typedef u32 u32x4 __attribute__((ext_vector_type(4)));

static __device__ __forceinline__ unsigned short bfb(float f) {
    return __builtin_bit_cast(unsigned short, (__bf16)f);   // HW RNE cvt
}
static __device__ __forceinline__ u32 pk2(float lo, float hi) {
    return (u32)bfb(lo) | ((u32)bfb(hi) << 16);
}

// ---- prep: K f32->bf16 flat; V f32 [s][d] -> bf16 transposed [d][s]
__global__ __launch_bounds__(256)
void prep_kv(const float* __restrict__ K, const float* __restrict__ V,
             unsigned short* __restrict__ Kbf, unsigned short* __restrict__ Vt) {
    const int bh = blockIdx.x >> 5;
    const int kvbase = (blockIdx.x & 31) << 6;

    const float* Ks = K + (size_t)bh * S_ * D_ + (size_t)kvbase * D_;
    unsigned short* Kd = Kbf + (size_t)bh * S_ * D_ + (size_t)kvbase * D_;
    #pragma unroll
    for (int i = 0; i < 4; ++i) {
        const int p = i * 256 + threadIdx.x;
        float4 x = reinterpret_cast<const float4*>(Ks)[p];
        u16x4 o = { bfb(x.x), bfb(x.y), bfb(x.z), bfb(x.w) };
        reinterpret_cast<u16x4*>(Kd)[p] = o;
    }

    __shared__ float Vl[64][65];
    const float* Vb = V + (size_t)bh * S_ * D_ + (size_t)kvbase * D_;
    #pragma unroll
    for (int i = 0; i < 4; ++i) {
        const int flat = i * 1024 + threadIdx.x * 4;
        const int kv = flat >> 6, d = flat & 63;
        float4 x = *reinterpret_cast<const float4*>(Vb + kv * D_ + d);
        Vl[kv][d] = x.x; Vl[kv][d + 1] = x.y; Vl[kv][d + 2] = x.z; Vl[kv][d + 3] = x.w;
    }
    __syncthreads();
    unsigned short* Vo = Vt + (size_t)bh * D_ * S_;
    #pragma unroll
    for (int i = 0; i < 2; ++i) {
        const int p = i * 256 + threadIdx.x;
        const int d = p >> 3, c = p & 7;
        u16x8 o;
        #pragma unroll
        for (int j = 0; j < 8; ++j) o[j] = bfb(Vl[c * 8 + j][d]);
        *reinterpret_cast<u16x8*>(Vo + d * S_ + kvbase + c * 8) = o;
    }
}

#define MFMA32(a, b, c) __builtin_amdgcn_mfma_f32_32x32x16_bf16((a), (b), (c), 0, 0, 0)

__global__ __launch_bounds__(128, 2)
void attn_fwd4(const float* __restrict__ Q, const unsigned short* __restrict__ Kbf,
               const unsigned short* __restrict__ Vtbf, float* __restrict__ O) {
    const int tid  = threadIdx.x;
    const int wq   = tid >> 6;          // wave -> q rows [wq*32, wq*32+32)
    const int lane = tid & 63;
    const int lq   = lane & 31;         // q col / kv row / d row
    const int hi   = lane >> 5;

    const int bid = blockIdx.x;
    const int qb  = 31 - (bid >> 5);    // heavy q-blocks dispatch first
    const int bh  = bid & 31;
    const int q0  = qb * 64 + wq * 32;

    const unsigned short* Kg = Kbf  + (size_t)bh * S_ * D_;
    const unsigned short* Vg = Vtbf + (size_t)bh * D_ * S_;

    __shared__ __align__(16) unsigned short Kl[2][4096];   // [64 kv][64 d] bf16
    __shared__ __align__(16) unsigned short Vl[2][4096];   // [64 d][64 kv] bf16

    // ---- Q B-frags: col=lane&31=q, k(d) = 16*ks + 8*hi + i; scaled log2(e)/8
    const float qscale = 0.18033688011112042f;
    bf16x8 qf[4];
    {
        const float* qsrc = Q + ((size_t)bh * S_ + q0 + lq) * D_;
        #pragma unroll
        for (int ks = 0; ks < 4; ++ks) {
            const float* p = qsrc + ks * 16 + hi * 8;
            float4 x = *reinterpret_cast<const float4*>(p);
            float4 y = *reinterpret_cast<const float4*>(p + 4);
            union { unsigned short u[8]; bf16x8 v; } t;
            t.u[0] = bfb(x.x * qscale); t.u[1] = bfb(x.y * qscale);
            t.u[2] = bfb(x.z * qscale); t.u[3] = bfb(x.w * qscale);
            t.u[4] = bfb(y.x * qscale); t.u[5] = bfb(y.y * qscale);
            t.u[6] = bfb(y.z * qscale); t.u[7] = bfb(y.w * qscale);
            qf[ks] = t.v;
        }
    }

    // ---- staging source pointers (per-lane, +const per tile)
    const unsigned short* kSrc[4];
    const unsigned short* vSrc[4];
    #pragma unroll
    for (int j = 0; j < 4; ++j) {
        const int p = j * 128 + tid, row = p >> 3;
        const int sc = (p & 7) ^ (row & 7);                // pre-swizzled source
        kSrc[j] = Kg + row * 64 + sc * 8;
        vSrc[j] = Vg + (size_t)row * S_ + sc * 8;
    }
    auto stage = [&](int buf, int t) {
        #pragma unroll
        for (int j = 0; j < 4; ++j) {
            const int p = j * 128 + tid;
            __builtin_amdgcn_global_load_lds(
                (const __attribute__((address_space(1))) void*)(kSrc[j] + t * 4096),
                (__attribute__((address_space(3))) void*)&Kl[buf][p * 8], 16, 0, 0);
            __builtin_amdgcn_global_load_lds(
                (const __attribute__((address_space(1))) void*)(vSrc[j] + t * 64),
                (__attribute__((address_space(3))) void*)&Vl[buf][p * 8], 16, 0, 0);
        }
    };

    f32x16 oa0, oa1;                    // O^T d-tiles [d 0-31][q], [d 32-63][q]
    #pragma unroll
    for (int r = 0; r < 16; ++r) { oa0[r] = 0.f; oa1[r] = 0.f; }
    float m_ = -__builtin_inff(), l_ = 0.f;

    const int nkv = qb + 1;
    stage(0, 0);
    __syncthreads();

    for (int t = 0; t < nkv; ++t) {
        if (t + 1 < nkv) stage((t + 1) & 1, t + 1);
        const unsigned short* Kb_ = Kl[t & 1];
        const unsigned short* Vb_ = Vl[t & 1];

        // ---- S^T = K · Q^T  (rows kv, cols q); A=K frags, B=Q frags
        f32x16 s0, s1;
        #pragma unroll
        for (int r = 0; r < 16; ++r) { s0[r] = 0.f; s1[r] = 0.f; }
        __builtin_amdgcn_s_setprio(1);
        #pragma unroll
        for (int ks = 0; ks < 4; ++ks) {
            const int cc = 2 * ks + hi;                    // 16B chunk of the d-row
            bf16x8 k0 = *reinterpret_cast<const bf16x8*>(
                &Kb_[((lq)*8      + (cc ^ (lq & 7))) * 8]);
            bf16x8 k1 = *reinterpret_cast<const bf16x8*>(
                &Kb_[((32 + lq)*8 + (cc ^ (lq & 7))) * 8]);
            s0 = MFMA32(k0, qf[ks], s0);
            s1 = MFMA32(k1, qf[ks], s1);
        }
        __builtin_amdgcn_s_setprio(0);

        // ---- causal mask (diagonal tile only); kv_row = (r&3)+8*(r>>2)+4*hi
        if (t == nkv - 1) {
            const int qg = q0 + lq - t * 64;
            #pragma unroll
            for (int r = 0; r < 16; ++r) {
                const int kv0 = (r & 3) + 8 * (r >> 2) + 4 * hi;
                if (kv0 > qg)      s0[r] = -__builtin_inff();
                if (kv0 + 32 > qg) s1[r] = -__builtin_inff();
            }
        }

        // ---- online softmax (base-2), per-lane scalar stats (one q-col/lane)
        float v = s0[0];
        #pragma unroll
        for (int r = 1; r < 16; ++r) v = fmaxf(v, s0[r]);
        #pragma unroll
        for (int r = 0; r < 16; ++r) v = fmaxf(v, s1[r]);
        v = fmaxf(v, __shfl_xor(v, 32));

        if (__any(v > m_ + 8.0f ? 1 : 0)) {                // defer-max (THR=8)
            const float mn = fmaxf(m_, v);
            const float al = __builtin_amdgcn_exp2f(m_ - mn);
            m_ = mn;
            l_ *= al;
            #pragma unroll
            for (int r = 0; r < 16; ++r) { oa0[r] *= al; oa1[r] *= al; }
        }
        #pragma unroll
        for (int r = 0; r < 16; ++r) {
            s0[r] = __builtin_amdgcn_exp2f(s0[r] - m_);
            s1[r] = __builtin_amdgcn_exp2f(s1[r] - m_);
        }
        {
            float rs = 0.f;
            #pragma unroll
            for (int r = 0; r < 16; ++r) rs += s0[r] + s1[r];
            rs += __shfl_xor(rs, 32);
            l_ += rs;
        }

        // ---- pack P^T to bf16 pairs: c[h][t][j] = kv {8t+2j, 8t+2j+1} + 4*hi
        u32 c0[4][2], c1[4][2];
        #pragma unroll
        for (int tq = 0; tq < 4; ++tq) {
            c0[tq][0] = pk2(s0[4*tq+0], s0[4*tq+1]);
            c0[tq][1] = pk2(s0[4*tq+2], s0[4*tq+3]);
            c1[tq][0] = pk2(s1[4*tq+0], s1[4*tq+1]);
            c1[tq][1] = pk2(s1[4*tq+2], s1[4*tq+3]);
        }

        // ---- O^T += V^T · P^T ; P^T B-frag via half-exchange
        __builtin_amdgcn_s_setprio(1);
#define PVSTEP(KS, C) { \
            const int tl = (2*(KS)) & 3; \
            u32 a0 = C[tl][0], a1 = C[tl][1], b0 = C[tl+1][0], b1 = C[tl+1][1]; \
            u32 pa0 = __shfl_xor(a0, 32), pa1 = __shfl_xor(a1, 32); \
            u32 pb0 = __shfl_xor(b0, 32), pb1 = __shfl_xor(b1, 32); \
            u32x4 w = { hi ? pb0 : a0, hi ? pb1 : a1, hi ? b0 : pa0, hi ? b1 : pa1 }; \
            bf16x8 pf = __builtin_bit_cast(bf16x8, w); \
            const int cc = 2*(KS) + hi; \
            bf16x8 v0 = *reinterpret_cast<const bf16x8*>( \
                &Vb_[((lq)*8      + (cc ^ (lq & 7))) * 8]); \
            bf16x8 v1 = *reinterpret_cast<const bf16x8*>( \
                &Vb_[((32 + lq)*8 + (cc ^ (lq & 7))) * 8]); \
            oa0 = MFMA32(v0, pf, oa0); \
            oa1 = MFMA32(v1, pf, oa1); }
        PVSTEP(0, c0) PVSTEP(1, c0) PVSTEP(2, c1) PVSTEP(3, c1)
#undef PVSTEP
        __builtin_amdgcn_s_setprio(0);

        __syncthreads();   // staged t+1 landed; reads of buf t done (both waves)
    }

    // ---- epilogue: O[q][d] = O^T / l ; d = (r&3) + 8*(r>>2) + 4*hi (+32)
    const float inv = 1.0f / l_;
    float* Ob = O + ((size_t)bh * S_ + q0 + lq) * D_;
    #pragma unroll
    for (int g = 0; g < 4; ++g) {
        float4 o0 = { oa0[4*g+0]*inv, oa0[4*g+1]*inv, oa0[4*g+2]*inv, oa0[4*g+3]*inv };
        *reinterpret_cast<float4*>(&Ob[8*g + 4*hi]) = o0;
        float4 o1 = { oa1[4*g+0]*inv, oa1[4*g+1]*inv, oa1[4*g+2]*inv, oa1[4*g+3]*inv };
        *reinterpret_cast<float4*>(&Ob[32 + 8*g + 4*hi]) = o1;
    }
}

extern "C" void kernel_launch(void* const* d_in, const int* in_sizes, int n_in,
                              void* d_out, int out_size, void* d_ws, size_t ws_size,
                              hipStream_t stream) {
    const float* Q = (const float*)d_in[0];
    const float* K = (const float*)d_in[1];
    const float* V = (const float*)d_in[2];
    // d_in[3] = mask: exact causal tril -> applied analytically.
    float* O = (float*)d_out;

    unsigned short* Kbf = (unsigned short*)d_ws;               // 8 MB
    unsigned short* Vt  = Kbf + (size_t)NBH * S_ * D_;         // 8 MB

    hipLaunchKernelGGL(prep_kv,   dim3(1024), dim3(256), 0, stream, K, V, Kbf, Vt);
    hipLaunchKernelGGL(attn_fwd4, dim3(1024), dim3(128), 0, stream, Q, Kbf, Vt, O);
}

// Round 6
// 152.483 us; speedup vs baseline: 1.3484x; 1.0096x over previous
//
#include <hip/hip_runtime.h>
#include <hip/hip_bf16.h>

// Causal SDPA, B=2 H=16 S=2048 D=64, fp32 in/out.
// R6: 4-wave blocks over a 128-q-row band share one K/V staging (halves
// stage/barrier overhead per work, ~8 resident waves/CU); P^T half-exchange
// via v_permlane32_swap_b32 (1 op builds both halves); row-sum via ones-MFMA.

#define S_ 2048
#define D_ 64
#define NBH 32

typedef __bf16 bf16x8 __attribute__((ext_vector_type(8)));
typedef float f32x16 __attribute__((ext_vector_type(16)));
typedef unsigned short u16x4 __attribute__((ext_vector_type(4)));
typedef unsigned short u16x8 __attribute__((ext_vector_type(8)));
typedef unsigned int u32;
typedef u32 u32x4 __attribute__((ext_vector_type(4)));

static __device__ __forceinline__ unsigned short bfb(float f) {
    return __builtin_bit_cast(unsigned short, (__bf16)f);   // HW RNE cvt
}
static __device__ __forceinline__ u32 pk2(float lo, float hi) {
    return (u32)bfb(lo) | ((u32)bfb(hi) << 16);
}

// ---- prep: K f32->bf16 flat; V f32 [s][d] -> bf16 transposed [d][s]
__global__ __launch_bounds__(256)
void prep_kv(const float* __restrict__ K, const float* __restrict__ V,
             unsigned short* __restrict__ Kbf, unsigned short* __restrict__ Vt) {
    const int bh = blockIdx.x >> 5;
    const int kvbase = (blockIdx.x & 31) << 6;

    const float* Ks = K + (size_t)bh * S_ * D_ + (size_t)kvbase * D_;
    unsigned short* Kd = Kbf + (size_t)bh * S_ * D_ + (size_t)kvbase * D_;
    #pragma unroll
    for (int i = 0; i < 4; ++i) {
        const int p = i * 256 + threadIdx.x;
        float4 x = reinterpret_cast<const float4*>(Ks)[p];
        u16x4 o = { bfb(x.x), bfb(x.y), bfb(x.z), bfb(x.w) };
        reinterpret_cast<u16x4*>(Kd)[p] = o;
    }

    __shared__ float Vl[64][65];
    const float* Vb = V + (size_t)bh * S_ * D_ + (size_t)kvbase * D_;
    #pragma unroll
    for (int i = 0; i < 4; ++i) {
        const int flat = i * 1024 + threadIdx.x * 4;
        const int kv = flat >> 6, d = flat & 63;
        float4 x = *reinterpret_cast<const float4*>(Vb + kv * D_ + d);
        Vl[kv][d] = x.x; Vl[kv][d + 1] = x.y; Vl[kv][d + 2] = x.z; Vl[kv][d + 3] = x.w;
    }
    __syncthreads();
    unsigned short* Vo = Vt + (size_t)bh * D_ * S_;
    #pragma unroll
    for (int i = 0; i < 2; ++i) {
        const int p = i * 256 + threadIdx.x;
        const int d = p >> 3, c = p & 7;
        u16x8 o;
        #pragma unroll
        for (int j = 0; j < 8; ++j) o[j] = bfb(Vl[c * 8 + j][d]);
        *reinterpret_cast<u16x8*>(Vo + d * S_ + kvbase + c * 8) = o;
    }
}

#define MFMA32(a, b, c) __builtin_amdgcn_mfma_f32_32x32x16_bf16((a), (b), (c), 0, 0, 0)

__global__ __launch_bounds__(256, 2)
void attn_fwd6(const float* __restrict__ Q, const unsigned short* __restrict__ Kbf,
               const unsigned short* __restrict__ Vtbf, float* __restrict__ O) {
    const int tid  = threadIdx.x;
    const int wq   = tid >> 6;          // wave -> q slice [q0w, q0w+32)
    const int lane = tid & 63;
    const int lq   = lane & 31;         // q col / kv row / d row
    const int hi   = lane >> 5;

    const int bid = blockIdx.x;
    const int bh  = bid & 31;           // same-bh blocks -> same XCD (stride 32)
    const int jb  = 15 - (bid >> 5);    // band, heavy-first
    const int q0w = jb * 128 + wq * 32;

    const int nkv_b = 2 * jb + 2;                 // block KV tiles
    const int nkv_w = 2 * jb + 1 + (wq >> 1);     // this wave's active tiles

    const unsigned short* Kg = Kbf  + (size_t)bh * S_ * D_;
    const unsigned short* Vg = Vtbf + (size_t)bh * D_ * S_;

    __shared__ __align__(16) unsigned short Kl[2][4096];   // [64 kv][64 d] bf16
    __shared__ __align__(16) unsigned short Vl[2][4096];   // [64 d][64 kv] bf16

    // ---- Q B-frags: col=lane&31=q, k(d) = 16*ks + 8*hi + i; scaled log2(e)/8
    const float qscale = 0.18033688011112042f;
    bf16x8 qf[4];
    {
        const float* qsrc = Q + ((size_t)bh * S_ + q0w + lq) * D_;
        #pragma unroll
        for (int ks = 0; ks < 4; ++ks) {
            const float* p = qsrc + ks * 16 + hi * 8;
            float4 x = *reinterpret_cast<const float4*>(p);
            float4 y = *reinterpret_cast<const float4*>(p + 4);
            union { unsigned short u[8]; bf16x8 v; } t;
            t.u[0] = bfb(x.x * qscale); t.u[1] = bfb(x.y * qscale);
            t.u[2] = bfb(x.z * qscale); t.u[3] = bfb(x.w * qscale);
            t.u[4] = bfb(y.x * qscale); t.u[5] = bfb(y.y * qscale);
            t.u[6] = bfb(y.z * qscale); t.u[7] = bfb(y.w * qscale);
            qf[ks] = t.v;
        }
    }

    bf16x8 ones;
    #pragma unroll
    for (int i = 0; i < 8; ++i) ones[i] = (__bf16)1.0f;

    // ---- staging: 256 threads x 2 chunks per tensor per tile
    const unsigned short* kSrc[2];
    const unsigned short* vSrc[2];
    #pragma unroll
    for (int i = 0; i < 2; ++i) {
        const int p = i * 256 + tid, row = p >> 3;
        const int sc = (p & 7) ^ (row & 7);                // pre-swizzled source
        kSrc[i] = Kg + row * 64 + sc * 8;
        vSrc[i] = Vg + (size_t)row * S_ + sc * 8;
    }
    auto stage = [&](int buf, int t) {
        #pragma unroll
        for (int i = 0; i < 2; ++i) {
            const int p = i * 256 + tid;
            __builtin_amdgcn_global_load_lds(
                (const __attribute__((address_space(1))) void*)(kSrc[i] + t * 4096),
                (__attribute__((address_space(3))) void*)&Kl[buf][p * 8], 16, 0, 0);
            __builtin_amdgcn_global_load_lds(
                (const __attribute__((address_space(1))) void*)(vSrc[i] + t * 64),
                (__attribute__((address_space(3))) void*)&Vl[buf][p * 8], 16, 0, 0);
        }
    };

    f32x16 oa0, oa1, ssum;              // O^T d-tiles + row-sum accumulator
    #pragma unroll
    for (int r = 0; r < 16; ++r) { oa0[r] = 0.f; oa1[r] = 0.f; ssum[r] = 0.f; }
    float m_ = -__builtin_inff();

    stage(0, 0);
    __syncthreads();

    for (int t = 0; t < nkv_b; ++t) {
        if (t + 1 < nkv_b) stage((t + 1) & 1, t + 1);
        if (t < nkv_w) {
            const unsigned short* Kb_ = Kl[t & 1];
            const unsigned short* Vb_ = Vl[t & 1];

            // ---- S^T = K · Q^T
            f32x16 s0, s1;
            #pragma unroll
            for (int r = 0; r < 16; ++r) { s0[r] = 0.f; s1[r] = 0.f; }
            __builtin_amdgcn_s_setprio(1);
            #pragma unroll
            for (int ks = 0; ks < 4; ++ks) {
                const int cc = 2 * ks + hi;
                bf16x8 k0 = *reinterpret_cast<const bf16x8*>(
                    &Kb_[((lq)*8      + (cc ^ (lq & 7))) * 8]);
                bf16x8 k1 = *reinterpret_cast<const bf16x8*>(
                    &Kb_[((32 + lq)*8 + (cc ^ (lq & 7))) * 8]);
                s0 = MFMA32(k0, qf[ks], s0);
                s1 = MFMA32(k1, qf[ks], s1);
            }
            __builtin_amdgcn_s_setprio(0);

            // ---- causal mask (this wave's diagonal tile only)
            if (t == nkv_w - 1) {
                const int qg = q0w + lq - t * 64;
                #pragma unroll
                for (int r = 0; r < 16; ++r) {
                    const int kv0 = (r & 3) + 8 * (r >> 2) + 4 * hi;
                    if (kv0 > qg)      s0[r] = -__builtin_inff();
                    if (kv0 + 32 > qg) s1[r] = -__builtin_inff();
                }
            }

            // ---- online softmax (base-2), per-lane stats (one q-col/lane)
            float v = s0[0];
            #pragma unroll
            for (int r = 1; r < 16; ++r) v = fmaxf(v, s0[r]);
            #pragma unroll
            for (int r = 0; r < 16; ++r) v = fmaxf(v, s1[r]);
            v = fmaxf(v, __shfl_xor(v, 32));

            if (__any(v > m_ + 8.0f ? 1 : 0)) {            // defer-max (THR=8)
                const float mn = fmaxf(m_, v);
                const float al = __builtin_amdgcn_exp2f(m_ - mn);
                m_ = mn;
                ssum[0] *= al;
                #pragma unroll
                for (int r = 0; r < 16; ++r) { oa0[r] *= al; oa1[r] *= al; }
            }
            #pragma unroll
            for (int r = 0; r < 16; ++r) {
                s0[r] = __builtin_amdgcn_exp2f(s0[r] - m_);
                s1[r] = __builtin_amdgcn_exp2f(s1[r] - m_);
            }

            // ---- pack P^T to bf16 pairs
            u32 c0[4][2], c1[4][2];
            #pragma unroll
            for (int tq = 0; tq < 4; ++tq) {
                c0[tq][0] = pk2(s0[4*tq+0], s0[4*tq+1]);
                c0[tq][1] = pk2(s0[4*tq+2], s0[4*tq+3]);
                c1[tq][0] = pk2(s1[4*tq+0], s1[4*tq+1]);
                c1[tq][1] = pk2(s1[4*tq+2], s1[4*tq+3]);
            }

            // ---- O^T += V^T · P^T ; half-exchange via permlane32_swap;
            //      row-sum via ones-MFMA (only ssum[0] is ever read)
            __builtin_amdgcn_s_setprio(1);
#define PVSTEP(KS, C, TL) { \
            u32 a0 = C[TL][0], a1 = C[TL][1], b0 = C[TL+1][0], b1 = C[TL+1][1]; \
            asm volatile("v_permlane32_swap_b32 %0, %1" : "+v"(a0), "+v"(b0)); \
            asm volatile("v_permlane32_swap_b32 %0, %1" : "+v"(a1), "+v"(b1)); \
            u32x4 w = { a0, a1, b0, b1 }; \
            bf16x8 pf = __builtin_bit_cast(bf16x8, w); \
            const int cc = 2*(KS) + hi; \
            bf16x8 v0 = *reinterpret_cast<const bf16x8*>( \
                &Vb_[((lq)*8      + (cc ^ (lq & 7))) * 8]); \
            bf16x8 v1 = *reinterpret_cast<const bf16x8*>( \
                &Vb_[((32 + lq)*8 + (cc ^ (lq & 7))) * 8]); \
            oa0 = MFMA32(v0, pf, oa0); \
            oa1 = MFMA32(v1, pf, oa1); \
            ssum = MFMA32(ones, pf, ssum); }
            PVSTEP(0, c0, 0) PVSTEP(1, c0, 2) PVSTEP(2, c1, 0) PVSTEP(3, c1, 2)
#undef PVSTEP
            __builtin_amdgcn_s_setprio(0);
        }
        __syncthreads();   // staged t+1 landed; all reads of buf t done
    }

    // ---- epilogue: O[q][d] = O^T / l ; d = (r&3) + 8*(r>>2) + 4*hi (+32)
    const float inv = 1.0f / ssum[0];
    float* Ob = O + ((size_t)bh * S_ + q0w + lq) * D_;
    #pragma unroll
    for (int g = 0; g < 4; ++g) {
        float4 o0 = { oa0[4*g+0]*inv, oa0[4*g+1]*inv, oa0[4*g+2]*inv, oa0[4*g+3]*inv };
        *reinterpret_cast<float4*>(&Ob[8*g + 4*hi]) = o0;
        float4 o1 = { oa1[4*g+0]*inv, oa1[4*g+1]*inv, oa1[4*g+2]*inv, oa1[4*g+3]*inv };
        *reinterpret_cast<float4*>(&Ob[32 + 8*g + 4*hi]) = o1;
    }
}

extern "C" void kernel_launch(void* const* d_in, const int* in_sizes, int n_in,
                              void* d_out, int out_size, void* d_ws, size_t ws_size,
                              hipStream_t stream) {
    const float* Q = (const float*)d_in[0];
    const float* K = (const float*)d_in[1];
    const float* V = (const float*)d_in[2];
    // d_in[3] = mask: exact causal tril -> applied analytically.
    float* O = (float*)d_out;

    unsigned short* Kbf = (unsigned short*)d_ws;               // 8 MB
    unsigned short* Vt  = Kbf + (size_t)NBH * S_ * D_;         // 8 MB

    hipLaunchKernelGGL(prep_kv,   dim3(1024), dim3(256), 0, stream, K, V, Kbf, Vt);
    hipLaunchKernelGGL(attn_fwd6, dim3(512),  dim3(256), 0, stream, Q, Kbf, Vt, O);
}